// Round 5
// baseline (466.379 us; speedup 1.0000x reference)
//
#include <hip/hip_runtime.h>

// Overlaps: out[i,j] = IoU(boxes0[i], boxes1[j]) if (label,batch) match else 0
// 1e8 fp32 outputs = 400 MB -> write-BW bound; kernel floor ~63 us @ 6.3 TB/s.
// R2-proven structure: 8 rows x 4 cols per thread, plain float4 stores.
// Keys fused into the main kernel (no separate dispatch, no workspace).

constexpr int ROWS_PER_BLOCK = 8;
constexpr int COLS_PER_BLOCK = 1024;  // 256 threads * 4 cols

__global__ __launch_bounds__(256, 8) void overlaps_kernel(
    const float4* __restrict__ boxes0,   // [n0] xyxy
    const int*    __restrict__ labels0,  // [n0]
    const int*    __restrict__ batches0, // [n0]
    const float4* __restrict__ boxes1,   // [n1]
    const int*    __restrict__ labels1,  // [n1]
    const int*    __restrict__ batches1, // [n1]
    float*        __restrict__ out,      // [n0, n1]
    int n0, int n1)
{
    const int j4 = blockIdx.x * COLS_PER_BLOCK + threadIdx.x * 4;
    if (j4 >= n1) return;

    const int r0   = blockIdx.y * ROWS_PER_BLOCK;
    const int rend = (r0 + ROWS_PER_BLOCK < n0) ? (r0 + ROWS_PER_BLOCK) : n0;

    if (j4 + 3 < n1) {
        // ---- column prologue: loaded once, reused for all rows ----
        const int4 l1v = *reinterpret_cast<const int4*>(labels1 + j4);
        const int4 t1v = *reinterpret_cast<const int4*>(batches1 + j4);
        float b1x[4], b1y[4], b1z[4], b1w[4], area1[4];
        int   k1[4];
        const int* lp = &l1v.x;
        const int* tp = &t1v.x;
        #pragma unroll
        for (int k = 0; k < 4; ++k) {
            const float4 b = boxes1[j4 + k];
            b1x[k] = b.x; b1y[k] = b.y; b1z[k] = b.z; b1w[k] = b.w;
            area1[k] = (b.z - b.x) * (b.w - b.y);
            k1[k] = (tp[k] << 16) | (lp[k] & 0xFFFF);
        }

        float* orow = out + (size_t)r0 * n1 + j4;

        #pragma unroll 8
        for (int r = r0; r < rend; ++r) {
            // block-uniform -> scalar loads
            const float4 b0 = boxes0[r];
            const int    k0 = (batches0[r] << 16) | (labels0[r] & 0xFFFF);
            const float  area0 = (b0.z - b0.x) * (b0.w - b0.y);

            float4 res;
            float* rp = &res.x;
            #pragma unroll
            for (int k = 0; k < 4; ++k) {
                const float x1 = fmaxf(b0.x, b1x[k]);
                const float y1 = fmaxf(b0.y, b1y[k]);
                const float x2 = fminf(b0.z, b1z[k]);
                const float y2 = fminf(b0.w, b1w[k]);
                const float inter = fmaxf(x2 - x1, 0.0f) * fmaxf(y2 - y1, 0.0f);
                const float uni = (area0 + area1[k]) - inter;
                float v = inter * __builtin_amdgcn_rcpf(uni);
                v = (uni > 0.0f) ? v : 0.0f;
                rp[k] = (k1[k] == k0) ? v : 0.0f;
            }
            *reinterpret_cast<float4*>(orow) = res;
            orow += n1;
        }
    } else {
        // scalar tail (n1 not a multiple of 4)
        for (int r = r0; r < rend; ++r) {
            const float4 b0 = boxes0[r];
            const int    k0 = (batches0[r] << 16) | (labels0[r] & 0xFFFF);
            const float  area0 = (b0.z - b0.x) * (b0.w - b0.y);
            for (int j = j4; j < n1; ++j) {
                float v = 0.0f;
                const int kj = (batches1[j] << 16) | (labels1[j] & 0xFFFF);
                if (kj == k0) {
                    const float4 bb = boxes1[j];
                    const float x1 = fmaxf(b0.x, bb.x);
                    const float y1 = fmaxf(b0.y, bb.y);
                    const float x2 = fminf(b0.z, bb.z);
                    const float y2 = fminf(b0.w, bb.w);
                    const float inter = fmaxf(x2 - x1, 0.0f) * fmaxf(y2 - y1, 0.0f);
                    const float area1 = (bb.z - bb.x) * (bb.w - bb.y);
                    const float uni = area0 + area1 - inter;
                    v = (uni > 0.0f) ? (inter / uni) : 0.0f;
                }
                out[(size_t)r * n1 + j] = v;
            }
        }
    }
}

extern "C" void kernel_launch(void* const* d_in, const int* in_sizes, int n_in,
                              void* d_out, int out_size, void* d_ws, size_t ws_size,
                              hipStream_t stream) {
    const float4* boxes0   = (const float4*)d_in[0];
    const int*    labels0  = (const int*)   d_in[1];
    const int*    batches0 = (const int*)   d_in[2];
    const float4* boxes1   = (const float4*)d_in[3];
    const int*    labels1  = (const int*)   d_in[4];
    const int*    batches1 = (const int*)   d_in[5];
    float*        out      = (float*)d_out;

    const int n0 = in_sizes[1];
    const int n1 = in_sizes[4];

    const int gx = (n1 + COLS_PER_BLOCK - 1) / COLS_PER_BLOCK;
    const int gy = (n0 + ROWS_PER_BLOCK - 1) / ROWS_PER_BLOCK;
    dim3 grid(gx, gy);

    overlaps_kernel<<<grid, 256, 0, stream>>>(
        boxes0, labels0, batches0, boxes1, labels1, batches1, out, n0, n1);
}

// Round 6
// 410.381 us; speedup vs baseline: 1.1365x; 1.1365x over previous
//
#include <hip/hip_runtime.h>

// Overlaps: out[i,j] = IoU(boxes0[i], boxes1[j]) if (label,batch) match else 0
// 1e8 fp32 outputs = 400 MB -> write-BW bound; kernel floor ~63 us @ 6.3 TB/s.
// R2-proven structure: 8 rows x 4 cols per thread, plain float4 stores,
// NO __launch_bounds__ min-waves (capping VGPRs at 64 caused spills -> regression
// in R4/R5). Keys fused into the main kernel (no separate dispatch).

constexpr int ROWS_PER_BLOCK = 8;
constexpr int COLS_PER_BLOCK = 1024;  // 256 threads * 4 cols

__global__ __launch_bounds__(256) void overlaps_kernel(
    const float4* __restrict__ boxes0,   // [n0] xyxy
    const int*    __restrict__ labels0,  // [n0]
    const int*    __restrict__ batches0, // [n0]
    const float4* __restrict__ boxes1,   // [n1]
    const int*    __restrict__ labels1,  // [n1]
    const int*    __restrict__ batches1, // [n1]
    float*        __restrict__ out,      // [n0, n1]
    int n0, int n1)
{
    const int j4 = blockIdx.x * COLS_PER_BLOCK + threadIdx.x * 4;
    if (j4 >= n1) return;

    const int r0   = blockIdx.y * ROWS_PER_BLOCK;
    const int rend = (r0 + ROWS_PER_BLOCK < n0) ? (r0 + ROWS_PER_BLOCK) : n0;

    if (j4 + 3 < n1) {
        // ---- column prologue: loaded once, reused for all rows ----
        const int4 l1v = *reinterpret_cast<const int4*>(labels1 + j4);
        const int4 t1v = *reinterpret_cast<const int4*>(batches1 + j4);
        const int* lp = &l1v.x;
        const int* tp = &t1v.x;
        float4 b1[4];
        float  area1[4];
        int    k1[4];
        #pragma unroll
        for (int k = 0; k < 4; ++k) {
            b1[k] = boxes1[j4 + k];
            area1[k] = (b1[k].z - b1[k].x) * (b1[k].w - b1[k].y);
            k1[k] = (tp[k] << 16) | (lp[k] & 0xFFFF);
        }

        float* orow = out + (size_t)r0 * n1 + j4;

        #pragma unroll 4
        for (int r = r0; r < rend; ++r) {
            // block-uniform -> scalar loads
            const float4 b0 = boxes0[r];
            const int    k0 = (batches0[r] << 16) | (labels0[r] & 0xFFFF);
            const float  area0 = (b0.z - b0.x) * (b0.w - b0.y);

            float4 res;
            float* rp = &res.x;
            #pragma unroll
            for (int k = 0; k < 4; ++k) {
                const float x1 = fmaxf(b0.x, b1[k].x);
                const float y1 = fmaxf(b0.y, b1[k].y);
                const float x2 = fminf(b0.z, b1[k].z);
                const float y2 = fminf(b0.w, b1[k].w);
                const float inter = fmaxf(x2 - x1, 0.0f) * fmaxf(y2 - y1, 0.0f);
                const float uni = (area0 + area1[k]) - inter;
                float v = inter * __builtin_amdgcn_rcpf(uni);
                v = (uni > 0.0f) ? v : 0.0f;
                rp[k] = (k1[k] == k0) ? v : 0.0f;
            }
            *reinterpret_cast<float4*>(orow) = res;
            orow += n1;
        }
    } else {
        // scalar tail (n1 not a multiple of 4)
        for (int r = r0; r < rend; ++r) {
            const float4 b0 = boxes0[r];
            const int    k0 = (batches0[r] << 16) | (labels0[r] & 0xFFFF);
            const float  area0 = (b0.z - b0.x) * (b0.w - b0.y);
            for (int j = j4; j < n1; ++j) {
                float v = 0.0f;
                const int kj = (batches1[j] << 16) | (labels1[j] & 0xFFFF);
                if (kj == k0) {
                    const float4 bb = boxes1[j];
                    const float x1 = fmaxf(b0.x, bb.x);
                    const float y1 = fmaxf(b0.y, bb.y);
                    const float x2 = fminf(b0.z, bb.z);
                    const float y2 = fminf(b0.w, bb.w);
                    const float inter = fmaxf(x2 - x1, 0.0f) * fmaxf(y2 - y1, 0.0f);
                    const float a1 = (bb.z - bb.x) * (bb.w - bb.y);
                    const float uni = area0 + a1 - inter;
                    v = (uni > 0.0f) ? (inter / uni) : 0.0f;
                }
                out[(size_t)r * n1 + j] = v;
            }
        }
    }
}

extern "C" void kernel_launch(void* const* d_in, const int* in_sizes, int n_in,
                              void* d_out, int out_size, void* d_ws, size_t ws_size,
                              hipStream_t stream) {
    const float4* boxes0   = (const float4*)d_in[0];
    const int*    labels0  = (const int*)   d_in[1];
    const int*    batches0 = (const int*)   d_in[2];
    const float4* boxes1   = (const float4*)d_in[3];
    const int*    labels1  = (const int*)   d_in[4];
    const int*    batches1 = (const int*)   d_in[5];
    float*        out      = (float*)d_out;

    const int n0 = in_sizes[1];
    const int n1 = in_sizes[4];

    const int gx = (n1 + COLS_PER_BLOCK - 1) / COLS_PER_BLOCK;
    const int gy = (n0 + ROWS_PER_BLOCK - 1) / ROWS_PER_BLOCK;
    dim3 grid(gx, gy);

    overlaps_kernel<<<grid, 256, 0, stream>>>(
        boxes0, labels0, batches0, boxes1, labels1, batches1, out, n0, n1);
}